// Round 1
// baseline (6899.073 us; speedup 1.0000x reference)
//
#include <hip/hip_runtime.h>
#include <hip/hip_bf16.h>
#include <math.h>

// Problem constants
// x: (2, 2048, 1024) fp32; Wq,Wk: (1024,1024); Wv: (1024,2048); Wo: (2048,1024)
// out: (2, 2048, 1024) fp32
// Heads: 4, d_qk=256, d_v=512, scale = 1/16, rope half=128, eps=1e-5
#define SEQ   2048
#define NROW  4096            // B*SEQ
#define DM    1024
#define LDQ   1024            // Q/K row stride (4 heads * 256)
#define LDV   2048            // V/O row stride (4 heads * 512)
#define NBLK  16              // 2048 / 128 row blocks per (b,h)

// ---------------------------------------------------------------------------
// Generic fp32 tiled GEMM: C[M,N] = A[M,K] * B[K,N], all row-major.
// 128x128 tile, BK=16, 256 threads, 8x8 micro-tile with strided mapping
// (rows tr+16i, cols tc+16j) so LDS reads are bank-conflict-free.
// ---------------------------------------------------------------------------
__global__ __launch_bounds__(256) void gemm_f32(
    const float* __restrict__ A, const float* __restrict__ B,
    float* __restrict__ C, int M, int N, int K)
{
  constexpr int BK = 16;
  __shared__ float As[BK][129];
  __shared__ float Bs[BK][129];
  const int tid = threadIdx.x;
  const int tr = tid >> 4, tc = tid & 15;
  const int bm = blockIdx.y, bn = blockIdx.x;
  float acc[8][8] = {};
  for (int k0 = 0; k0 < K; k0 += BK) {
    {
      const int m  = tid >> 1;
      const int kk = (tid & 1) << 3;
      const float* ap = A + (size_t)(bm * 128 + m) * K + k0 + kk;
      #pragma unroll
      for (int j = 0; j < 8; ++j) As[kk + j][m] = ap[j];
      const int n  = tid & 127;
      const int kb = (tid >> 7) << 3;
      const float* bp = B + (size_t)(k0 + kb) * N + bn * 128 + n;
      #pragma unroll
      for (int j = 0; j < 8; ++j) Bs[kb + j][n] = bp[(size_t)j * N];
    }
    __syncthreads();
    #pragma unroll
    for (int k = 0; k < BK; ++k) {
      float a[8], b[8];
      #pragma unroll
      for (int i = 0; i < 8; ++i) a[i] = As[k][tr + 16 * i];
      #pragma unroll
      for (int j = 0; j < 8; ++j) b[j] = Bs[k][tc + 16 * j];
      #pragma unroll
      for (int i = 0; i < 8; ++i)
        #pragma unroll
        for (int j = 0; j < 8; ++j) acc[i][j] += a[i] * b[j];
    }
    __syncthreads();
  }
  #pragma unroll
  for (int i = 0; i < 8; ++i) {
    float* cp = C + (size_t)(bm * 128 + tr + 16 * i) * N + bn * 128 + tc;
    #pragma unroll
    for (int j = 0; j < 8; ++j) cp[16 * j] = acc[i][j];
  }
}

// ---------------------------------------------------------------------------
// RoPE applied in place to Q and K. One thread per (row, head, f).
// ---------------------------------------------------------------------------
__global__ void rope_kernel(float* __restrict__ Q, float* __restrict__ K)
{
  const int idx = blockIdx.x * 256 + threadIdx.x;   // < 4096*4*128 = 2097152
  const int f   = idx & 127;
  const int h   = (idx >> 7) & 3;
  const int row = idx >> 9;            // 0..4095
  const int pos = row & (SEQ - 1);     // position within the sequence
  // inv_freq = 10000^(-f/128) ; ln(10000) = 9.210340371976184
  const float inv = expf(-(float)f * (9.210340371976184f / 128.f));
  float s, c;
  sincosf((float)pos * inv, &s, &c);
  const size_t base = (size_t)row * LDQ + h * 256 + f;
  const float q1 = Q[base], q2 = Q[base + 128];
  Q[base]       = q1 * c - q2 * s;
  Q[base + 128] = q2 * c + q1 * s;
  const float k1 = K[base], k2 = K[base + 128];
  K[base]       = k1 * c - k2 * s;
  K[base + 128] = k2 * c + k1 * s;
}

// ---------------------------------------------------------------------------
// Diagonal block solve at step t (right-looking blocked forward substitution).
// grid (4 col-chunks, 8 bh), 256 threads.
// L = tril(exp(K_t K_t^T / 16)) + eps*I computed on the fly (phase 1),
// then 128 columns solved in parallel, one thread each (phase 2). In-place on V.
// ---------------------------------------------------------------------------
__global__ __launch_bounds__(256) void diag_solve(
    const float* __restrict__ K, float* __restrict__ V, int t)
{
  __shared__ float Ls[128][129];   // 66.0 KB
  __shared__ float Ks[128][33];    // 16.9 KB
  __shared__ float Xs[128][128];   // 64.0 KB  (total 147 KB <= 160 KB)
  const int bh = blockIdx.y, cc = blockIdx.x;
  const int b = bh >> 2, h = bh & 3;
  const int tid = threadIdx.x;
  const int tr = tid >> 4, tc = tid & 15;
  const float* Kbase = K + (size_t)b * SEQ * LDQ + (size_t)h * 256;
  float* Vp = V + (size_t)b * SEQ * LDV + (size_t)h * 512 + cc * 128;

  // Phase 1: L = exp(K_t K_t^T / 16), tril + eps on diag
  float acc[8][8] = {};
  for (int kk = 0; kk < 256; kk += 32) {
    {
      const int r = tid >> 1, c0 = (tid & 1) * 16;
      const float* kp = Kbase + (size_t)(t * 128 + r) * LDQ + kk + c0;
      #pragma unroll
      for (int jx = 0; jx < 16; ++jx) Ks[r][c0 + jx] = kp[jx];
    }
    __syncthreads();
    for (int k = 0; k < 32; ++k) {
      float a[8], bb[8];
      #pragma unroll
      for (int i = 0; i < 8; ++i) a[i]  = Ks[tr + 16 * i][k];
      #pragma unroll
      for (int j = 0; j < 8; ++j) bb[j] = Ks[tc + 16 * j][k];
      #pragma unroll
      for (int i = 0; i < 8; ++i)
        #pragma unroll
        for (int j = 0; j < 8; ++j) acc[i][j] += a[i] * bb[j];
    }
    __syncthreads();
  }
  #pragma unroll
  for (int i = 0; i < 8; ++i)
    #pragma unroll
    for (int j = 0; j < 8; ++j) {
      const int rr = tr + 16 * i, cl = tc + 16 * j;
      float v;
      if (cl < rr)       v = __expf(acc[i][j] * 0.0625f);
      else if (cl == rr) v = __expf(acc[i][j] * 0.0625f) + 1e-5f;
      else               v = 0.f;
      Ls[rr][cl] = v;
    }
  // Load RHS chunk (128 rows x 128 cols)
  {
    const int r = tid >> 1, c0 = (tid & 1) * 64;
    const float* vp = Vp + (size_t)(t * 128 + r) * LDV + c0;
    #pragma unroll
    for (int jx = 0; jx < 64; ++jx) Xs[r][c0 + jx] = vp[jx];
  }
  __syncthreads();
  // Phase 2: forward substitution, one thread per column
  if (tid < 128) {
    const int c = tid;
    for (int r = 0; r < 128; ++r) {
      float s0 = 0.f, s1 = 0.f, s2 = 0.f, s3 = 0.f;
      int j = 0;
      for (; j + 4 <= r; j += 4) {
        s0 += Ls[r][j]     * Xs[j][c];
        s1 += Ls[r][j + 1] * Xs[j + 1][c];
        s2 += Ls[r][j + 2] * Xs[j + 2][c];
        s3 += Ls[r][j + 3] * Xs[j + 3][c];
      }
      for (; j < r; ++j) s0 += Ls[r][j] * Xs[j][c];
      const float s = Xs[r][c] - ((s0 + s1) + (s2 + s3));
      Xs[r][c] = s / Ls[r][r];
    }
  }
  __syncthreads();
  // Write back solved block
  {
    const int r = tid >> 1, c0 = (tid & 1) * 64;
    float* vp = Vp + (size_t)(t * 128 + r) * LDV + c0;
    #pragma unroll
    for (int jx = 0; jx < 64; ++jx) vp[jx] = Xs[r][c0 + jx];
  }
}

// ---------------------------------------------------------------------------
// Trailing update at step t: for row-block ib > t:
//   V_ib -= exp(K_ib K_t^T / 16) @ sol_t
// grid (15 - t, 8 bh), 256 threads. S (128x128) staged in LDS.
// ---------------------------------------------------------------------------
__global__ __launch_bounds__(256) void solve_update(
    const float* __restrict__ K, float* __restrict__ V, int t)
{
  __shared__ float Ss[128][129];      // 66.0 KB
  __shared__ float Sbuf[128 * 130];   // 66.6 KB (staging union)
  const int bh = blockIdx.y;
  const int b = bh >> 2, h = bh & 3;
  const int ib = t + 1 + blockIdx.x;
  const int tid = threadIdx.x;
  const int tr = tid >> 4, tc = tid & 15;
  const float* Kbase = K + (size_t)b * SEQ * LDQ + (size_t)h * 256;
  float* Vhead = V + (size_t)b * SEQ * LDV + (size_t)h * 512;

  // Phase 1: S = exp(K_ib . K_t^T / 16)  (strictly below diagonal: no mask)
  float (*Ks1)[65] = (float(*)[65])Sbuf;
  float (*Ks2)[65] = (float(*)[65])(Sbuf + 128 * 65);
  float acc1[8][8] = {};
  for (int kk = 0; kk < 256; kk += 64) {
    {
      const int r = tid >> 1, c0 = (tid & 1) * 32;
      const float* p1 = Kbase + (size_t)(ib * 128 + r) * LDQ + kk + c0;
      const float* p2 = Kbase + (size_t)(t  * 128 + r) * LDQ + kk + c0;
      #pragma unroll
      for (int jx = 0; jx < 32; ++jx) Ks1[r][c0 + jx] = p1[jx];
      #pragma unroll
      for (int jx = 0; jx < 32; ++jx) Ks2[r][c0 + jx] = p2[jx];
    }
    __syncthreads();
    for (int k = 0; k < 64; ++k) {
      float a[8], bb[8];
      #pragma unroll
      for (int i = 0; i < 8; ++i) a[i]  = Ks1[tr + 16 * i][k];
      #pragma unroll
      for (int j = 0; j < 8; ++j) bb[j] = Ks2[tc + 16 * j][k];
      #pragma unroll
      for (int i = 0; i < 8; ++i)
        #pragma unroll
        for (int j = 0; j < 8; ++j) acc1[i][j] += a[i] * bb[j];
    }
    __syncthreads();
  }
  #pragma unroll
  for (int i = 0; i < 8; ++i)
    #pragma unroll
    for (int j = 0; j < 8; ++j)
      Ss[tr + 16 * i][tc + 16 * j] = __expf(acc1[i][j] * 0.0625f);
  __syncthreads();

  // Phase 2: V_ib -= S @ sol_t (sol_t = V rows t*128.., cols of this head)
  float (*Bs)[129] = (float(*)[129])Sbuf;
  #pragma unroll
  for (int cc = 0; cc < 4; ++cc) {
    {
      const int r = tid >> 1, c0 = (tid & 1) * 64;
      const float* bp = Vhead + (size_t)(t * 128 + r) * LDV + cc * 128 + c0;
      #pragma unroll
      for (int jx = 0; jx < 64; ++jx) Bs[r][c0 + jx] = bp[jx];
    }
    __syncthreads();
    float acc2[8][8] = {};
    for (int k = 0; k < 128; ++k) {
      float a[8], bb[8];
      #pragma unroll
      for (int i = 0; i < 8; ++i) a[i]  = Ss[tr + 16 * i][k];
      #pragma unroll
      for (int j = 0; j < 8; ++j) bb[j] = Bs[k][tc + 16 * j];
      #pragma unroll
      for (int i = 0; i < 8; ++i)
        #pragma unroll
        for (int j = 0; j < 8; ++j) acc2[i][j] += a[i] * bb[j];
    }
    #pragma unroll
    for (int i = 0; i < 8; ++i) {
      float* vp = Vhead + (size_t)(ib * 128 + tr + 16 * i) * LDV + cc * 128 + tc;
      #pragma unroll
      for (int j = 0; j < 8; ++j) vp[16 * j] -= acc2[i][j];
    }
    __syncthreads();
  }
}

// ---------------------------------------------------------------------------
// O = tril(exp(Q K^T / 16)) @ sol, fused flash-style over j-blocks.
// grid (16 iblocks, 8 bh), 512 threads. Per-thread 8x16 output micro-tile.
// ---------------------------------------------------------------------------
__global__ __launch_bounds__(512) void o_kernel(
    const float* __restrict__ Q, const float* __restrict__ K,
    const float* __restrict__ V, float* __restrict__ O)
{
  __shared__ float Ss[128][129];      // 66.0 KB
  __shared__ float Sbuf[128 * 130];   // 66.6 KB
  const int ib = blockIdx.x, bh = blockIdx.y;
  const int b = bh >> 2, h = bh & 3;
  const int tid = threadIdx.x;
  const int tg_r = tid >> 5;   // 0..15
  const int tg_c = tid & 31;   // 0..31
  const float* Qbase = Q + (size_t)b * SEQ * LDQ + (size_t)h * 256;
  const float* Kbase = K + (size_t)b * SEQ * LDQ + (size_t)h * 256;
  const float* Vhead = V + (size_t)b * SEQ * LDV + (size_t)h * 512;
  float* Ohead       = O + (size_t)b * SEQ * LDV + (size_t)h * 512;

  float acc[8][16] = {};
  for (int jb = 0; jb <= ib; ++jb) {
    // Phase 1: S = exp(Q_ib K_jb^T / 16), tril-masked on the diagonal block
    float (*Qs)[65] = (float(*)[65])Sbuf;
    float (*Ks)[65] = (float(*)[65])(Sbuf + 128 * 65);
    float acc1[8][4] = {};
    for (int kk = 0; kk < 256; kk += 64) {
      {
        const int r = tid >> 2, c0 = (tid & 3) * 16;
        const float* qp = Qbase + (size_t)(ib * 128 + r) * LDQ + kk + c0;
        const float* kp = Kbase + (size_t)(jb * 128 + r) * LDQ + kk + c0;
        #pragma unroll
        for (int jx = 0; jx < 16; ++jx) Qs[r][c0 + jx] = qp[jx];
        #pragma unroll
        for (int jx = 0; jx < 16; ++jx) Ks[r][c0 + jx] = kp[jx];
      }
      __syncthreads();
      for (int k = 0; k < 64; ++k) {
        float a[8], bb[4];
        #pragma unroll
        for (int i = 0; i < 8; ++i) a[i]  = Qs[tg_r + 16 * i][k];
        #pragma unroll
        for (int j = 0; j < 4; ++j) bb[j] = Ks[tg_c + 32 * j][k];
        #pragma unroll
        for (int i = 0; i < 8; ++i)
          #pragma unroll
          for (int j = 0; j < 4; ++j) acc1[i][j] += a[i] * bb[j];
      }
      __syncthreads();
    }
    #pragma unroll
    for (int i = 0; i < 8; ++i)
      #pragma unroll
      for (int j = 0; j < 4; ++j) {
        const int rr = tg_r + 16 * i, cl = tg_c + 32 * j;
        float e = __expf(acc1[i][j] * 0.0625f);
        if (jb == ib && cl > rr) e = 0.f;
        Ss[rr][cl] = e;
      }
    __syncthreads();
    // Phase 2: acc += S @ sol_jb
    float (*Bs)[129] = (float(*)[129])Sbuf;
    #pragma unroll
    for (int cc = 0; cc < 4; ++cc) {
      {
        const int r = tid >> 2, c0 = (tid & 3) * 32;
        const float* bp = Vhead + (size_t)(jb * 128 + r) * LDV + cc * 128 + c0;
        #pragma unroll
        for (int jx = 0; jx < 32; ++jx) Bs[r][c0 + jx] = bp[jx];
      }
      __syncthreads();
      for (int k = 0; k < 128; ++k) {
        float a[8], bb[4];
        #pragma unroll
        for (int i = 0; i < 8; ++i)  a[i]   = Ss[tg_r + 16 * i][k];
        #pragma unroll
        for (int jj = 0; jj < 4; ++jj) bb[jj] = Bs[k][tg_c + 32 * jj];
        #pragma unroll
        for (int i = 0; i < 8; ++i)
          #pragma unroll
          for (int jj = 0; jj < 4; ++jj) acc[i][4 * cc + jj] += a[i] * bb[jj];
      }
      __syncthreads();
    }
  }
  #pragma unroll
  for (int i = 0; i < 8; ++i)
    #pragma unroll
    for (int m = 0; m < 16; ++m) {
      const int cc = m >> 2, jj = m & 3;
      const int col = cc * 128 + 32 * jj + tg_c;
      Ohead[(size_t)(ib * 128 + tg_r + 16 * i) * LDV + col] = acc[i][m];
    }
}

// ---------------------------------------------------------------------------
extern "C" void kernel_launch(void* const* d_in, const int* in_sizes, int n_in,
                              void* d_out, int out_size, void* d_ws, size_t ws_size,
                              hipStream_t stream)
{
  const float* x  = (const float*)d_in[0];
  const float* Wq = (const float*)d_in[1];
  const float* Wk = (const float*)d_in[2];
  const float* Wv = (const float*)d_in[3];
  const float* Wo = (const float*)d_in[4];
  float* out = (float*)d_out;

  // Workspace layout (fp32): Q 16MB | K 16MB | V(->sol, in place) 32MB | O 32MB
  float* Q = (float*)d_ws;
  float* K = Q + (size_t)NROW * LDQ;
  float* V = K + (size_t)NROW * LDQ;
  float* O = V + (size_t)NROW * LDV;

  // Projections
  gemm_f32<<<dim3(DM / 128, NROW / 128), 256, 0, stream>>>(x, Wq, Q, NROW, DM, DM);
  gemm_f32<<<dim3(DM / 128, NROW / 128), 256, 0, stream>>>(x, Wk, K, NROW, DM, DM);
  gemm_f32<<<dim3(LDV / 128, NROW / 128), 256, 0, stream>>>(x, Wv, V, NROW, LDV, DM);

  // RoPE on Q and K
  rope_kernel<<<(NROW * 4 * 128) / 256, 256, 0, stream>>>(Q, K);

  // Blocked forward substitution: A = tril(exp(KK^T/16)) + eps I, solve A sol = V
  for (int t = 0; t < NBLK; ++t) {
    diag_solve<<<dim3(4, 8), 256, 0, stream>>>(K, V, t);
    if (t < NBLK - 1)
      solve_update<<<dim3(NBLK - 1 - t, 8), 256, 0, stream>>>(K, V, t);
  }

  // O = tril(exp(QK^T/16)) @ sol
  o_kernel<<<dim3(NBLK, 8), 512, 0, stream>>>(Q, K, V, O);

  // out = O @ Wo
  gemm_f32<<<dim3(DM / 128, NROW / 128), 256, 0, stream>>>(O, Wo, out, NROW, DM, LDV);
}

// Round 2
// 6007.843 us; speedup vs baseline: 1.1483x; 1.1483x over previous
//
#include <hip/hip_runtime.h>
#include <hip/hip_bf16.h>
#include <math.h>

// Problem constants
// x: (2, 2048, 1024) fp32; Wq,Wk: (1024,1024); Wv: (1024,2048); Wo: (2048,1024)
// out: (2, 2048, 1024) fp32
// Heads: 4, d_qk=256, d_v=512, scale = 1/16, rope half=128, eps=1e-5
#define SEQ   2048
#define NROW  4096            // B*SEQ
#define DM    1024
#define LDQ   1024            // Q/K row stride (4 heads * 256)
#define LDV   2048            // V/O row stride (4 heads * 512)
#define NBLK  16              // 2048 / 128 row blocks per (b,h)

typedef float f32x4 __attribute__((ext_vector_type(4)));
typedef int   i32x4 __attribute__((ext_vector_type(4)));

__device__ inline void mfma_bf16_16x16x32(f32x4& d, i32x4 a, i32x4 b) {
  asm("v_mfma_f32_16x16x32_bf16 %0, %1, %2, %0" : "+v"(d) : "v"(a), "v"(b));
}

__device__ inline ushort f2bf(float f) {
  __hip_bfloat16 h = __float2bfloat16(f);
  return *(ushort*)&h;
}

// ---------------------------------------------------------------------------
// Packing kernels: rearrange fp32 matrices into bf16 "k-chunk-major" MFMA
// operand layout: pack[blk][kc][r][j] = Mat(element with k = kc*8+j), where
//  - A-operand (MxK): blk = row/128, r = row%128, k = col
//  - B-operand (KxN): blk = col/128, r = col%128, k = row
// A 128x64 K-step tile is then 16KB of CONTIGUOUS memory, and MFMA fragment
// reads (b128 per lane) are LDS bank-conflict-free.
// ---------------------------------------------------------------------------
__global__ void pack_x_kernel(const float* __restrict__ X, ushort* __restrict__ P)
{
  // X: 4096 x 1024 row-major; K8 = 128
  const int t = blockIdx.x * 256 + threadIdx.x;   // < 4096*128
  const int kc = t & 127;
  const int m  = t >> 7;
  const float* src = X + (size_t)m * DM + kc * 8;
  f32x4 v0 = *(const f32x4*)src;
  f32x4 v1 = *(const f32x4*)(src + 4);
  ushort o[8];
  #pragma unroll
  for (int j = 0; j < 4; ++j) { o[j] = f2bf(v0[j]); o[4 + j] = f2bf(v1[j]); }
  ushort* dst = P + ((size_t)((m >> 7) * 128 + kc) * 128 + (m & 127)) * 8;
  *(i32x4*)dst = *(i32x4*)o;
}

__global__ void pack_w_kernel(const float* __restrict__ W, ushort* __restrict__ P,
                              int K, int N)
{
  const int K8 = K >> 3;
  const int t = blockIdx.x * 256 + threadIdx.x;   // < N*K/8
  const int c  = t & 127;
  const int kc = (t >> 7) % K8;
  const int nb = t / (128 * K8);
  ushort o[8];
  #pragma unroll
  for (int j = 0; j < 8; ++j)
    o[j] = f2bf(W[(size_t)(kc * 8 + j) * N + nb * 128 + c]);
  ushort* dst = P + ((size_t)(nb * K8 + kc) * 128 + c) * 8;
  *(i32x4*)dst = *(i32x4*)o;
}

// ---------------------------------------------------------------------------
// bf16 MFMA GEMM: C[M,N] fp32 = Apack * Bpack. 128x128 tile, BK=64,
// 256 threads = 4 waves in 2x2, each wave a 64x64 quadrant (4x4 fragments
// of 16x16x32). Single-buffered LDS, reg-staged global->LDS.
// ---------------------------------------------------------------------------
__global__ __launch_bounds__(256) void gemm_bf16(
    const ushort* __restrict__ Ap, const ushort* __restrict__ Bp,
    float* __restrict__ C, int M, int N, int K)
{
  __shared__ __align__(16) ushort a_lds[8][128][8];  // 16 KB
  __shared__ __align__(16) ushort b_lds[8][128][8];  // 16 KB
  const int tid  = threadIdx.x;
  const int lane = tid & 63;
  const int w    = tid >> 6;
  const int wr   = w >> 1, wc = w & 1;
  const int mb = blockIdx.y, nb = blockIdx.x;
  const int K8 = K >> 3;
  const ushort* aT = Ap + (size_t)mb * K8 * 1024;   // 128*8 els per kc
  const ushort* bT = Bp + (size_t)nb * K8 * 1024;
  const int lr = lane & 15;
  const int lk = lane >> 4;

  f32x4 acc[4][4];
  #pragma unroll
  for (int i = 0; i < 4; ++i)
    #pragma unroll
    for (int j = 0; j < 4; ++j) acc[i][j] = (f32x4)(0.f);

  for (int kc0 = 0; kc0 < K8; kc0 += 8) {
    i32x4 av[4], bv[4];
    const ushort* asrc = aT + (size_t)kc0 * 1024;
    const ushort* bsrc = bT + (size_t)kc0 * 1024;
    #pragma unroll
    for (int it = 0; it < 4; ++it) {
      av[it] = *(const i32x4*)(asrc + it * 2048 + tid * 8);
      bv[it] = *(const i32x4*)(bsrc + it * 2048 + tid * 8);
    }
    __syncthreads();   // previous iteration's LDS reads complete
    #pragma unroll
    for (int it = 0; it < 4; ++it) {
      *(i32x4*)((ushort*)a_lds + it * 2048 + tid * 8) = av[it];
      *(i32x4*)((ushort*)b_lds + it * 2048 + tid * 8) = bv[it];
    }
    __syncthreads();
    #pragma unroll
    for (int kk = 0; kk < 2; ++kk) {
      i32x4 af[4], bf[4];
      #pragma unroll
      for (int m = 0; m < 4; ++m)
        af[m] = *(const i32x4*)&a_lds[kk * 4 + lk][wr * 64 + m * 16 + lr][0];
      #pragma unroll
      for (int n = 0; n < 4; ++n)
        bf[n] = *(const i32x4*)&b_lds[kk * 4 + lk][wc * 64 + n * 16 + lr][0];
      #pragma unroll
      for (int m = 0; m < 4; ++m)
        #pragma unroll
        for (int n = 0; n < 4; ++n)
          mfma_bf16_16x16x32(acc[m][n], af[m], bf[n]);
    }
  }
  asm volatile("s_nop 7\ns_nop 7\ns_nop 7");   // MFMA->VALU/VMEM read hazard
  const int r0 = (lane >> 4) * 4;
  #pragma unroll
  for (int m = 0; m < 4; ++m)
    #pragma unroll
    for (int n = 0; n < 4; ++n) {
      const int row = mb * 128 + wr * 64 + m * 16 + r0;
      const int col = nb * 128 + wc * 64 + n * 16 + lr;
      float* cp = C + (size_t)row * N + col;
      #pragma unroll
      for (int q = 0; q < 4; ++q) cp[(size_t)q * N] = acc[m][n][q];
    }
}

// ---------------------------------------------------------------------------
// RoPE applied in place to Q and K. One thread per (row, head, f).
// ---------------------------------------------------------------------------
__global__ void rope_kernel(float* __restrict__ Q, float* __restrict__ K)
{
  const int idx = blockIdx.x * 256 + threadIdx.x;   // < 4096*4*128 = 2097152
  const int f   = idx & 127;
  const int h   = (idx >> 7) & 3;
  const int row = idx >> 9;            // 0..4095
  const int pos = row & (SEQ - 1);     // position within the sequence
  const float inv = expf(-(float)f * (9.210340371976184f / 128.f));
  float s, c;
  sincosf((float)pos * inv, &s, &c);
  const size_t base = (size_t)row * LDQ + h * 256 + f;
  const float q1 = Q[base], q2 = Q[base + 128];
  Q[base]       = q1 * c - q2 * s;
  Q[base + 128] = q2 * c + q1 * s;
  const float k1 = K[base], k2 = K[base + 128];
  K[base]       = k1 * c - k2 * s;
  K[base + 128] = k2 * c + k1 * s;
}

// ---------------------------------------------------------------------------
// Diagonal block solve at step t (right-looking blocked forward substitution).
// ---------------------------------------------------------------------------
__global__ __launch_bounds__(256) void diag_solve(
    const float* __restrict__ K, float* __restrict__ V, int t)
{
  __shared__ float Ls[128][129];
  __shared__ float Ks[128][33];
  __shared__ float Xs[128][128];
  const int bh = blockIdx.y, cc = blockIdx.x;
  const int b = bh >> 2, h = bh & 3;
  const int tid = threadIdx.x;
  const int tr = tid >> 4, tc = tid & 15;
  const float* Kbase = K + (size_t)b * SEQ * LDQ + (size_t)h * 256;
  float* Vp = V + (size_t)b * SEQ * LDV + (size_t)h * 512 + cc * 128;

  float acc[8][8] = {};
  for (int kk = 0; kk < 256; kk += 32) {
    {
      const int r = tid >> 1, c0 = (tid & 1) * 16;
      const float* kp = Kbase + (size_t)(t * 128 + r) * LDQ + kk + c0;
      #pragma unroll
      for (int jx = 0; jx < 16; ++jx) Ks[r][c0 + jx] = kp[jx];
    }
    __syncthreads();
    for (int k = 0; k < 32; ++k) {
      float a[8], bb[8];
      #pragma unroll
      for (int i = 0; i < 8; ++i) a[i]  = Ks[tr + 16 * i][k];
      #pragma unroll
      for (int j = 0; j < 8; ++j) bb[j] = Ks[tc + 16 * j][k];
      #pragma unroll
      for (int i = 0; i < 8; ++i)
        #pragma unroll
        for (int j = 0; j < 8; ++j) acc[i][j] += a[i] * bb[j];
    }
    __syncthreads();
  }
  #pragma unroll
  for (int i = 0; i < 8; ++i)
    #pragma unroll
    for (int j = 0; j < 8; ++j) {
      const int rr = tr + 16 * i, cl = tc + 16 * j;
      float v;
      if (cl < rr)       v = __expf(acc[i][j] * 0.0625f);
      else if (cl == rr) v = __expf(acc[i][j] * 0.0625f) + 1e-5f;
      else               v = 0.f;
      Ls[rr][cl] = v;
    }
  {
    const int r = tid >> 1, c0 = (tid & 1) * 64;
    const float* vp = Vp + (size_t)(t * 128 + r) * LDV + c0;
    #pragma unroll
    for (int jx = 0; jx < 64; ++jx) Xs[r][c0 + jx] = vp[jx];
  }
  __syncthreads();
  if (tid < 128) {
    const int c = tid;
    for (int r = 0; r < 128; ++r) {
      float s0 = 0.f, s1 = 0.f, s2 = 0.f, s3 = 0.f;
      int j = 0;
      for (; j + 4 <= r; j += 4) {
        s0 += Ls[r][j]     * Xs[j][c];
        s1 += Ls[r][j + 1] * Xs[j + 1][c];
        s2 += Ls[r][j + 2] * Xs[j + 2][c];
        s3 += Ls[r][j + 3] * Xs[j + 3][c];
      }
      for (; j < r; ++j) s0 += Ls[r][j] * Xs[j][c];
      const float s = Xs[r][c] - ((s0 + s1) + (s2 + s3));
      Xs[r][c] = s / Ls[r][r];
    }
  }
  __syncthreads();
  {
    const int r = tid >> 1, c0 = (tid & 1) * 64;
    float* vp = Vp + (size_t)(t * 128 + r) * LDV + c0;
    #pragma unroll
    for (int jx = 0; jx < 64; ++jx) vp[jx] = Xs[r][c0 + jx];
  }
}

// ---------------------------------------------------------------------------
// Trailing update at step t: V_ib -= exp(K_ib K_t^T / 16) @ sol_t
// ---------------------------------------------------------------------------
__global__ __launch_bounds__(256) void solve_update(
    const float* __restrict__ K, float* __restrict__ V, int t)
{
  __shared__ float Ss[128][129];
  __shared__ float Sbuf[128 * 130];
  const int bh = blockIdx.y;
  const int b = bh >> 2, h = bh & 3;
  const int ib = t + 1 + blockIdx.x;
  const int tid = threadIdx.x;
  const int tr = tid >> 4, tc = tid & 15;
  const float* Kbase = K + (size_t)b * SEQ * LDQ + (size_t)h * 256;
  float* Vhead = V + (size_t)b * SEQ * LDV + (size_t)h * 512;

  float (*Ks1)[65] = (float(*)[65])Sbuf;
  float (*Ks2)[65] = (float(*)[65])(Sbuf + 128 * 65);
  float acc1[8][8] = {};
  for (int kk = 0; kk < 256; kk += 64) {
    {
      const int r = tid >> 1, c0 = (tid & 1) * 32;
      const float* p1 = Kbase + (size_t)(ib * 128 + r) * LDQ + kk + c0;
      const float* p2 = Kbase + (size_t)(t  * 128 + r) * LDQ + kk + c0;
      #pragma unroll
      for (int jx = 0; jx < 32; ++jx) Ks1[r][c0 + jx] = p1[jx];
      #pragma unroll
      for (int jx = 0; jx < 32; ++jx) Ks2[r][c0 + jx] = p2[jx];
    }
    __syncthreads();
    for (int k = 0; k < 64; ++k) {
      float a[8], bb[8];
      #pragma unroll
      for (int i = 0; i < 8; ++i) a[i]  = Ks1[tr + 16 * i][k];
      #pragma unroll
      for (int j = 0; j < 8; ++j) bb[j] = Ks2[tc + 16 * j][k];
      #pragma unroll
      for (int i = 0; i < 8; ++i)
        #pragma unroll
        for (int j = 0; j < 8; ++j) acc1[i][j] += a[i] * bb[j];
    }
    __syncthreads();
  }
  #pragma unroll
  for (int i = 0; i < 8; ++i)
    #pragma unroll
    for (int j = 0; j < 8; ++j)
      Ss[tr + 16 * i][tc + 16 * j] = __expf(acc1[i][j] * 0.0625f);
  __syncthreads();

  float (*Bs)[129] = (float(*)[129])Sbuf;
  #pragma unroll
  for (int cc = 0; cc < 4; ++cc) {
    {
      const int r = tid >> 1, c0 = (tid & 1) * 64;
      const float* bp = Vhead + (size_t)(t * 128 + r) * LDV + cc * 128 + c0;
      #pragma unroll
      for (int jx = 0; jx < 64; ++jx) Bs[r][c0 + jx] = bp[jx];
    }
    __syncthreads();
    float acc2[8][8] = {};
    for (int k = 0; k < 128; ++k) {
      float a[8], bb[8];
      #pragma unroll
      for (int i = 0; i < 8; ++i) a[i]  = Ss[tr + 16 * i][k];
      #pragma unroll
      for (int j = 0; j < 8; ++j) bb[j] = Bs[k][tc + 16 * j];
      #pragma unroll
      for (int i = 0; i < 8; ++i)
        #pragma unroll
        for (int j = 0; j < 8; ++j) acc2[i][j] += a[i] * bb[j];
    }
    #pragma unroll
    for (int i = 0; i < 8; ++i) {
      float* vp = Vhead + (size_t)(ib * 128 + tr + 16 * i) * LDV + cc * 128 + tc;
      #pragma unroll
      for (int j = 0; j < 8; ++j) vp[16 * j] -= acc2[i][j];
    }
    __syncthreads();
  }
}

// ---------------------------------------------------------------------------
// O = tril(exp(Q K^T / 16)) @ sol, fused flash-style over j-blocks.
// Writes O directly as bf16 in A-pack layout (for the final MFMA GEMM).
// ---------------------------------------------------------------------------
__global__ __launch_bounds__(512) void o_kernel(
    const float* __restrict__ Q, const float* __restrict__ K,
    const float* __restrict__ V, ushort* __restrict__ Opack)
{
  __shared__ float Ss[128][129];
  __shared__ float Sbuf[128 * 130];
  const int ib = blockIdx.x, bh = blockIdx.y;
  const int b = bh >> 2, h = bh & 3;
  const int tid = threadIdx.x;
  const int tg_r = tid >> 5;   // 0..15
  const int tg_c = tid & 31;   // 0..31
  const float* Qbase = Q + (size_t)b * SEQ * LDQ + (size_t)h * 256;
  const float* Kbase = K + (size_t)b * SEQ * LDQ + (size_t)h * 256;
  const float* Vhead = V + (size_t)b * SEQ * LDV + (size_t)h * 512;

  float acc[8][16] = {};
  for (int jb = 0; jb <= ib; ++jb) {
    float (*Qs)[65] = (float(*)[65])Sbuf;
    float (*Ks)[65] = (float(*)[65])(Sbuf + 128 * 65);
    float acc1[8][4] = {};
    for (int kk = 0; kk < 256; kk += 64) {
      {
        const int r = tid >> 2, c0 = (tid & 3) * 16;
        const float* qp = Qbase + (size_t)(ib * 128 + r) * LDQ + kk + c0;
        const float* kp = Kbase + (size_t)(jb * 128 + r) * LDQ + kk + c0;
        #pragma unroll
        for (int jx = 0; jx < 16; ++jx) Qs[r][c0 + jx] = qp[jx];
        #pragma unroll
        for (int jx = 0; jx < 16; ++jx) Ks[r][c0 + jx] = kp[jx];
      }
      __syncthreads();
      for (int k = 0; k < 64; ++k) {
        float a[8], bb[4];
        #pragma unroll
        for (int i = 0; i < 8; ++i) a[i]  = Qs[tg_r + 16 * i][k];
        #pragma unroll
        for (int j = 0; j < 4; ++j) bb[j] = Ks[tg_c + 32 * j][k];
        #pragma unroll
        for (int i = 0; i < 8; ++i)
          #pragma unroll
          for (int j = 0; j < 4; ++j) acc1[i][j] += a[i] * bb[j];
      }
      __syncthreads();
    }
    #pragma unroll
    for (int i = 0; i < 8; ++i)
      #pragma unroll
      for (int j = 0; j < 4; ++j) {
        const int rr = tg_r + 16 * i, cl = tg_c + 32 * j;
        float e = __expf(acc1[i][j] * 0.0625f);
        if (jb == ib && cl > rr) e = 0.f;
        Ss[rr][cl] = e;
      }
    __syncthreads();
    float (*Bs)[129] = (float(*)[129])Sbuf;
    #pragma unroll
    for (int cc = 0; cc < 4; ++cc) {
      {
        const int r = tid >> 2, c0 = (tid & 3) * 32;
        const float* bp = Vhead + (size_t)(jb * 128 + r) * LDV + cc * 128 + c0;
        #pragma unroll
        for (int jx = 0; jx < 32; ++jx) Bs[r][c0 + jx] = bp[jx];
      }
      __syncthreads();
      for (int k = 0; k < 128; ++k) {
        float a[8], bb[4];
        #pragma unroll
        for (int i = 0; i < 8; ++i)  a[i]   = Ss[tg_r + 16 * i][k];
        #pragma unroll
        for (int jj = 0; jj < 4; ++jj) bb[jj] = Bs[k][tg_c + 32 * jj];
        #pragma unroll
        for (int i = 0; i < 8; ++i)
          #pragma unroll
          for (int jj = 0; jj < 4; ++jj) acc[i][4 * cc + jj] += a[i] * bb[jj];
      }
      __syncthreads();
    }
  }
  // Epilogue: write O as bf16 A-pack: Opack[rowblk][kc][r][j], K8 = 256.
  const int row_blk = b * 16 + ib;
  #pragma unroll
  for (int i = 0; i < 8; ++i) {
    const int r = tg_r + 16 * i;
    #pragma unroll
    for (int m = 0; m < 16; ++m) {
      const int cc = m >> 2, jj = m & 3;
      const int col = h * 512 + cc * 128 + 32 * jj + tg_c;  // 0..2047
      const int kc = col >> 3, j = col & 7;
      Opack[((size_t)row_blk * 256 + kc) * 1024 + r * 8 + j] = f2bf(acc[i][m]);
    }
  }
}

// ---------------------------------------------------------------------------
extern "C" void kernel_launch(void* const* d_in, const int* in_sizes, int n_in,
                              void* d_out, int out_size, void* d_ws, size_t ws_size,
                              hipStream_t stream)
{
  const float* x  = (const float*)d_in[0];
  const float* Wq = (const float*)d_in[1];
  const float* Wk = (const float*)d_in[2];
  const float* Wv = (const float*)d_in[3];
  const float* Wo = (const float*)d_in[4];
  float* out = (float*)d_out;

  // Workspace layout (84 MB total):
  //  [0,16MB):  xpack(8) | Wqp(2) | Wkp(2) | Wvp(4)   -- later reused as Opack(16)
  //  [16,20MB): Wop(4)
  //  [20,36MB): Q fp32   [36,52MB): K fp32   [52,84MB): V fp32
  char* base = (char*)d_ws;
  ushort* xpack = (ushort*)(base);
  ushort* Wqp   = (ushort*)(base + (8u  << 20));
  ushort* Wkp   = (ushort*)(base + (10u << 20));
  ushort* Wvp   = (ushort*)(base + (12u << 20));
  ushort* Opack = (ushort*)(base);              // aliases xpack..Wvp after proj
  ushort* Wop   = (ushort*)(base + (16u << 20));
  float*  Q     = (float*) (base + (20u << 20));
  float*  K     = (float*) (base + (36u << 20));
  float*  V     = (float*) (base + (52u << 20));

  // Pack inputs to bf16 MFMA layouts
  pack_x_kernel<<<(NROW * 128) / 256, 256, 0, stream>>>(x, xpack);
  pack_w_kernel<<<(1024 * 1024 / 8) / 256, 256, 0, stream>>>(Wq, Wqp, 1024, 1024);
  pack_w_kernel<<<(1024 * 1024 / 8) / 256, 256, 0, stream>>>(Wk, Wkp, 1024, 1024);
  pack_w_kernel<<<(1024 * 2048 / 8) / 256, 256, 0, stream>>>(Wv, Wvp, 1024, 2048);
  pack_w_kernel<<<(2048 * 1024 / 8) / 256, 256, 0, stream>>>(Wo, Wop, 2048, 1024);

  // Projections (bf16 MFMA, fp32 out)
  gemm_bf16<<<dim3(DM / 128, NROW / 128), 256, 0, stream>>>(xpack, Wqp, Q, NROW, DM, DM);
  gemm_bf16<<<dim3(DM / 128, NROW / 128), 256, 0, stream>>>(xpack, Wkp, K, NROW, DM, DM);
  gemm_bf16<<<dim3(LDV / 128, NROW / 128), 256, 0, stream>>>(xpack, Wvp, V, NROW, LDV, DM);

  // RoPE on Q and K (fp32, in place)
  rope_kernel<<<(NROW * 4 * 128) / 256, 256, 0, stream>>>(Q, K);

  // Blocked forward substitution: A = tril(exp(KK^T/16)) + eps I, solve A sol = V
  for (int t = 0; t < NBLK; ++t) {
    diag_solve<<<dim3(4, 8), 256, 0, stream>>>(K, V, t);
    if (t < NBLK - 1)
      solve_update<<<dim3(NBLK - 1 - t, 8), 256, 0, stream>>>(K, V, t);
  }

  // O = tril(exp(QK^T/16)) @ sol  -> bf16 Opack (overwrites xpack/W packs)
  o_kernel<<<dim3(NBLK, 8), 512, 0, stream>>>(Q, K, V, Opack);

  // out = O @ Wo (bf16 MFMA)
  gemm_bf16<<<dim3(DM / 128, NROW / 128), 256, 0, stream>>>(Opack, Wop, out, NROW, DM, LDV);
}

// Round 5
// 2438.294 us; speedup vs baseline: 2.8295x; 2.4640x over previous
//
#include <hip/hip_runtime.h>
#include <hip/hip_bf16.h>
#include <math.h>

// Problem constants
#define SEQ   2048
#define NROW  4096            // B*SEQ
#define DM    1024
#define LDQ   1024            // Q/K row stride (4 heads * 256)
#define LDV   2048            // V/O row stride (4 heads * 512)
#define NBLK  16              // 2048 / 128 row blocks per (b,h)

typedef float  f32x4  __attribute__((ext_vector_type(4)));
typedef int    i32x4  __attribute__((ext_vector_type(4)));
typedef __bf16 bf16x8 __attribute__((ext_vector_type(8)));

// Compiler-managed MFMA: hazards/NOPs/spills handled by the backend.
#define MFMA(d, a, b) (d) = __builtin_amdgcn_mfma_f32_16x16x32_bf16((a), (b), (d), 0, 0, 0)

__device__ inline ushort f2bf(float f) {
  __hip_bfloat16 h = __float2bfloat16(f);
  return *(ushort*)&h;
}
__device__ inline float bf2f(ushort u) {
  return __uint_as_float((unsigned)u << 16);
}
// v ~= bf2f(hi) + bf2f(lo), residual ~ 2^-18 * |v|
__device__ inline void split2(float v, ushort& hi, ushort& lo) {
  hi = f2bf(v);
  lo = f2bf(v - bf2f(hi));
}
__device__ inline bf16x8 ldfrag(const ushort* p) { return *(const bf16x8*)p; }

// ---------------------------------------------------------------------------
// Packing kernels (bf16 "k-chunk-major" MFMA operand layout):
// pack[blk][kc][r][j] holds element with k = kc*8+j.
// ---------------------------------------------------------------------------
__global__ void pack_x_kernel(const float* __restrict__ X, ushort* __restrict__ P)
{
  const int t = blockIdx.x * 256 + threadIdx.x;   // < 4096*128
  const int kc = t & 127;
  const int m  = t >> 7;
  const float* src = X + (size_t)m * DM + kc * 8;
  f32x4 v0 = *(const f32x4*)src;
  f32x4 v1 = *(const f32x4*)(src + 4);
  ushort o[8];
  #pragma unroll
  for (int j = 0; j < 4; ++j) { o[j] = f2bf(v0[j]); o[4 + j] = f2bf(v1[j]); }
  ushort* dst = P + ((size_t)((m >> 7) * 128 + kc) * 128 + (m & 127)) * 8;
  *(i32x4*)dst = *(i32x4*)o;
}

__global__ void pack_w_kernel(const float* __restrict__ W, ushort* __restrict__ P,
                              int K, int N)
{
  const int K8 = K >> 3;
  const int t = blockIdx.x * 256 + threadIdx.x;   // < N*K/8
  const int c  = t & 127;
  const int kc = (t >> 7) % K8;
  const int nb = t / (128 * K8);
  ushort o[8];
  #pragma unroll
  for (int j = 0; j < 8; ++j)
    o[j] = f2bf(W[(size_t)(kc * 8 + j) * N + nb * 128 + c]);
  ushort* dst = P + ((size_t)(nb * K8 + kc) * 128 + c) * 8;
  *(i32x4*)dst = *(i32x4*)o;
}

// fp32 matrix (4096x1024, post-RoPE Q or K) -> hi/lo bf16 packs, per-(bh,
// 128-row-block) layout: [(bh*16+tb)][kc 0..31][r 0..127][8] over head dim 256.
__global__ void pack_split_kernel(const float* __restrict__ M,
                                  ushort* __restrict__ Phi, ushort* __restrict__ Plo)
{
  const int idx = blockIdx.x * 256 + threadIdx.x;  // < 4096*128
  const int c8  = idx & 127;
  const int row = idx >> 7;
  const int col0 = c8 * 8;
  const int h = col0 >> 8;
  const int d = col0 & 255;
  const int b = row >> 11;
  const int r = row & 127;
  const int tb = (row & 2047) >> 7;
  const int bh = b * 4 + h;
  const float* src = M + (size_t)row * LDQ + col0;
  ushort oh[8], ol[8];
  #pragma unroll
  for (int j = 0; j < 8; ++j) split2(src[j], oh[j], ol[j]);
  const size_t doff = (((size_t)(bh * 16 + tb) * 32 + (d >> 3)) * 128 + r) * 8;
  *(i32x4*)(Phi + doff) = *(i32x4*)oh;
  *(i32x4*)(Plo + doff) = *(i32x4*)ol;
}

// ---------------------------------------------------------------------------
// bf16 MFMA GEMM: C[M,N] fp32 = Apack * Bpack. 128x128 tile, 4 waves 2x2.
// ---------------------------------------------------------------------------
__global__ __launch_bounds__(256) void gemm_bf16(
    const ushort* __restrict__ Ap, const ushort* __restrict__ Bp,
    float* __restrict__ C, int M, int N, int K)
{
  __shared__ __align__(16) ushort a_lds[8][128][8];
  __shared__ __align__(16) ushort b_lds[8][128][8];
  const int tid  = threadIdx.x;
  const int lane = tid & 63;
  const int w    = tid >> 6;
  const int wr   = w >> 1, wc = w & 1;
  const int mb = blockIdx.y, nb = blockIdx.x;
  const int K8 = K >> 3;
  const ushort* aT = Ap + (size_t)mb * K8 * 1024;
  const ushort* bT = Bp + (size_t)nb * K8 * 1024;
  const int lr = lane & 15;
  const int lk = lane >> 4;

  f32x4 acc[4][4];
  #pragma unroll
  for (int i = 0; i < 4; ++i)
    #pragma unroll
    for (int j = 0; j < 4; ++j) acc[i][j] = (f32x4)(0.f);

  for (int kc0 = 0; kc0 < K8; kc0 += 8) {
    i32x4 av[4], bv[4];
    const ushort* asrc = aT + (size_t)kc0 * 1024;
    const ushort* bsrc = bT + (size_t)kc0 * 1024;
    #pragma unroll
    for (int it = 0; it < 4; ++it) {
      av[it] = *(const i32x4*)(asrc + it * 2048 + tid * 8);
      bv[it] = *(const i32x4*)(bsrc + it * 2048 + tid * 8);
    }
    __syncthreads();
    #pragma unroll
    for (int it = 0; it < 4; ++it) {
      *(i32x4*)((ushort*)a_lds + it * 2048 + tid * 8) = av[it];
      *(i32x4*)((ushort*)b_lds + it * 2048 + tid * 8) = bv[it];
    }
    __syncthreads();
    #pragma unroll
    for (int kk = 0; kk < 2; ++kk) {
      bf16x8 af[4], bf[4];
      #pragma unroll
      for (int m = 0; m < 4; ++m)
        af[m] = ldfrag(&a_lds[kk * 4 + lk][wr * 64 + m * 16 + lr][0]);
      #pragma unroll
      for (int n = 0; n < 4; ++n)
        bf[n] = ldfrag(&b_lds[kk * 4 + lk][wc * 64 + n * 16 + lr][0]);
      #pragma unroll
      for (int m = 0; m < 4; ++m)
        #pragma unroll
        for (int n = 0; n < 4; ++n)
          MFMA(acc[m][n], af[m], bf[n]);
    }
  }
  const int r0 = (lane >> 4) * 4;
  #pragma unroll
  for (int m = 0; m < 4; ++m)
    #pragma unroll
    for (int n = 0; n < 4; ++n) {
      const int row = mb * 128 + wr * 64 + m * 16 + r0;
      const int col = nb * 128 + wc * 64 + n * 16 + lr;
      float* cp = C + (size_t)row * N + col;
      #pragma unroll
      for (int q = 0; q < 4; ++q) cp[(size_t)q * N] = acc[m][n][q];
    }
}

// ---------------------------------------------------------------------------
// RoPE applied in place to Q and K (fp32).
// ---------------------------------------------------------------------------
__global__ void rope_kernel(float* __restrict__ Q, float* __restrict__ K)
{
  const int idx = blockIdx.x * 256 + threadIdx.x;   // < 4096*4*128
  const int f   = idx & 127;
  const int h   = (idx >> 7) & 3;
  const int row = idx >> 9;
  const int pos = row & (SEQ - 1);
  const float inv = expf(-(float)f * (9.210340371976184f / 128.f));
  float s, c;
  sincosf((float)pos * inv, &s, &c);
  const size_t base = (size_t)row * LDQ + h * 256 + f;
  const float q1 = Q[base], q2 = Q[base + 128];
  Q[base]       = q1 * c - q2 * s;
  Q[base + 128] = q2 * c + q1 * s;
  const float k1 = K[base], k2 = K[base + 128];
  K[base]       = k1 * c - k2 * s;
  K[base + 128] = k2 * c + k1 * s;
}

// ---------------------------------------------------------------------------
// winv: L = tril(exp(K_t K_t^T/16)) + eps*I via split-MFMA Gram, fp32 invert,
// store W = L^-1 as SPLIT bf16 A-packs (Whi + Wlo).
// ---------------------------------------------------------------------------
__global__ __launch_bounds__(256) void winv_kernel(
    const ushort* __restrict__ Khi, const ushort* __restrict__ Klo,
    ushort* __restrict__ Whi, ushort* __restrict__ Wlo)
{
  __shared__ float L[128][129];
  __shared__ float W[128][129];
  const int t = blockIdx.x, bh = blockIdx.y;
  const int tid = threadIdx.x;
  const int lane = tid & 63, w = tid >> 6;
  const int wr = w >> 1, wc = w & 1;
  const int lr = lane & 15, lk = lane >> 4;
  const size_t kb = (size_t)(bh * 16 + t) * 32768;

  f32x4 acc[4][4];
  #pragma unroll
  for (int i = 0; i < 4; ++i)
    #pragma unroll
    for (int j = 0; j < 4; ++j) acc[i][j] = (f32x4)(0.f);
  #pragma unroll
  for (int ks = 0; ks < 8; ++ks) {
    bf16x8 ah[4], al[4];
    #pragma unroll
    for (int m = 0; m < 4; ++m) {
      const size_t off = kb + ((size_t)(ks * 4 + lk) * 128 + wr * 64 + m * 16 + lr) * 8;
      ah[m] = ldfrag(Khi + off);
      al[m] = ldfrag(Klo + off);
    }
    #pragma unroll
    for (int n = 0; n < 4; ++n) {
      const size_t off = kb + ((size_t)(ks * 4 + lk) * 128 + wc * 64 + n * 16 + lr) * 8;
      bf16x8 bh_ = ldfrag(Khi + off);
      bf16x8 bl_ = ldfrag(Klo + off);
      #pragma unroll
      for (int m = 0; m < 4; ++m) {
        MFMA(acc[m][n], ah[m], bh_);
        MFMA(acc[m][n], ah[m], bl_);
        MFMA(acc[m][n], al[m], bh_);
      }
    }
  }
  for (int i = tid; i < 128 * 129; i += 256) ((float*)W)[i] = 0.f;
  #pragma unroll
  for (int m = 0; m < 4; ++m)
    #pragma unroll
    for (int n = 0; n < 4; ++n)
      #pragma unroll
      for (int q = 0; q < 4; ++q) {
        const int row = wr * 64 + m * 16 + lk * 4 + q;
        const int col = wc * 64 + n * 16 + lr;
        float v = __expf(acc[m][n][q] * 0.0625f);
        if (row == col) v += 1e-5f;
        L[row][col] = v;
      }
  __syncthreads();
  if (tid < 128) {
    const int c = tid;
    W[c][c] = 1.f / L[c][c];
    for (int r = c + 1; r < 128; ++r) {
      float s0 = 0.f, s1 = 0.f, s2 = 0.f, s3 = 0.f;
      int j = c;
      for (; j + 4 <= r; j += 4) {
        s0 += L[r][j]     * W[j][c];
        s1 += L[r][j + 1] * W[j + 1][c];
        s2 += L[r][j + 2] * W[j + 2][c];
        s3 += L[r][j + 3] * W[j + 3][c];
      }
      for (; j < r; ++j) s0 += L[r][j] * W[j][c];
      W[r][c] = -((s0 + s1) + (s2 + s3)) / L[r][r];
    }
  }
  __syncthreads();
  const size_t wb = (size_t)(bh * 16 + t) * 16384;
  for (int i = tid; i < 2048; i += 256) {
    const int kc = i >> 7, r = i & 127;
    ushort oh[8], ol[8];
    #pragma unroll
    for (int j = 0; j < 8; ++j) split2(W[r][kc * 8 + j], oh[j], ol[j]);
    *(i32x4*)(Whi + wb + (size_t)i * 8) = *(i32x4*)oh;
    *(i32x4*)(Wlo + wb + (size_t)i * 8) = *(i32x4*)ol;
  }
}

// ---------------------------------------------------------------------------
// apply_w0: sol_0 = W_0 @ V_0 (split-MFMA, in place on V).
// ---------------------------------------------------------------------------
__global__ __launch_bounds__(256) void apply_w0_kernel(
    const ushort* __restrict__ Whi, const ushort* __restrict__ Wlo,
    float* __restrict__ V)
{
  __shared__ __align__(16) ushort shi[16 * 128 * 8];
  __shared__ __align__(16) ushort slo[16 * 128 * 8];
  const int bh = blockIdx.x;
  const int b = bh >> 2, h = bh & 3;
  const int tid = threadIdx.x;
  const int lane = tid & 63, w = tid >> 6;
  const int wr = w >> 1, wc = w & 1, lr = lane & 15, lk = lane >> 4;
  const size_t wb = (size_t)(bh * 16) * 16384;
  float* Vrows = V + (size_t)b * SEQ * LDV + h * 512;

  for (int cc = 0; cc < 4; ++cc) {
    if (cc) __syncthreads();
    {
      const int k = tid >> 1, c0 = (tid & 1) * 64;
      const float* vp = Vrows + (size_t)k * LDV + cc * 128 + c0;
      for (int c = 0; c < 64; ++c) {
        ushort hi, lo;
        split2(vp[c], hi, lo);
        const int idx = (((k >> 3) * 128) + c0 + c) * 8 + (k & 7);
        shi[idx] = hi; slo[idx] = lo;
      }
    }
    __syncthreads();
    f32x4 acc[4][4];
    #pragma unroll
    for (int i = 0; i < 4; ++i)
      #pragma unroll
      for (int j = 0; j < 4; ++j) acc[i][j] = (f32x4)(0.f);
    #pragma unroll
    for (int ks = 0; ks < 4; ++ks) {
      bf16x8 ah[4], al[4];
      #pragma unroll
      for (int m = 0; m < 4; ++m) {
        const size_t off = wb + ((size_t)(ks * 4 + lk) * 128 + wr * 64 + m * 16 + lr) * 8;
        ah[m] = ldfrag(Whi + off);
        al[m] = ldfrag(Wlo + off);
      }
      #pragma unroll
      for (int n = 0; n < 4; ++n) {
        const int idx = (((ks * 4 + lk) * 128) + wc * 64 + n * 16 + lr) * 8;
        bf16x8 bh_ = ldfrag(&shi[idx]);
        bf16x8 bl_ = ldfrag(&slo[idx]);
        #pragma unroll
        for (int m = 0; m < 4; ++m) {
          MFMA(acc[m][n], ah[m], bh_);
          MFMA(acc[m][n], ah[m], bl_);
          MFMA(acc[m][n], al[m], bh_);
        }
      }
    }
    #pragma unroll
    for (int m = 0; m < 4; ++m)
      #pragma unroll
      for (int n = 0; n < 4; ++n) {
        const int col = wc * 64 + n * 16 + lr;
        #pragma unroll
        for (int q = 0; q < 4; ++q) {
          const int row = wr * 64 + m * 16 + lk * 4 + q;
          Vrows[(size_t)row * LDV + cc * 128 + col] = acc[m][n][q];
        }
      }
  }
}

// ---------------------------------------------------------------------------
// solve_step(t): trailing blocks ib > t:  V_ib -= exp(K_ib K_t^T/16) @ sol_t
// (split-bf16 MFMA). Lead block (ib == t+1) then applies W_{t+1} to its
// freshly updated rhs (register -> split LDS) producing sol_{t+1} in place.
// ---------------------------------------------------------------------------
__global__ __launch_bounds__(256) void solve_step_kernel(
    const ushort* __restrict__ Khi, const ushort* __restrict__ Klo,
    const ushort* __restrict__ Whi, const ushort* __restrict__ Wlo,
    float* __restrict__ V, int t)
{
  __shared__ __align__(16) ushort pAhi[16 * 128 * 8];  // 32 KB
  __shared__ __align__(16) ushort pAlo[16 * 128 * 8];  // 32 KB
  __shared__ __align__(16) ushort shi[16 * 128 * 8];   // 32 KB
  __shared__ __align__(16) ushort slo[16 * 128 * 8];   // 32 KB
  const int ib = t + 1 + blockIdx.x;
  const int bh = blockIdx.y;
  const int b = bh >> 2, h = bh & 3;
  const bool lead = (blockIdx.x == 0);
  const int tid = threadIdx.x;
  const int lane = tid & 63, w = tid >> 6;
  const int wr = w >> 1, wc = w & 1, lr = lane & 15, lk = lane >> 4;
  const size_t kbi = (size_t)(bh * 16 + ib) * 32768;
  const size_t kbt = (size_t)(bh * 16 + t) * 32768;
  float* Vhead = V + (size_t)b * SEQ * LDV + h * 512;
  const float* SolT = Vhead + (size_t)t * 128 * LDV;
  float* Vib = Vhead + (size_t)ib * 128 * LDV;

  // Phase A: S = exp(K_ib K_t^T / 16) -> split A-pack (k = t-row index)
  {
    f32x4 a1[4][4];
    #pragma unroll
    for (int i = 0; i < 4; ++i)
      #pragma unroll
      for (int j = 0; j < 4; ++j) a1[i][j] = (f32x4)(0.f);
    #pragma unroll
    for (int ks = 0; ks < 8; ++ks) {
      bf16x8 ah[4], al[4];
      #pragma unroll
      for (int m = 0; m < 4; ++m) {
        const size_t off = kbi + ((size_t)(ks * 4 + lk) * 128 + wr * 64 + m * 16 + lr) * 8;
        ah[m] = ldfrag(Khi + off);
        al[m] = ldfrag(Klo + off);
      }
      #pragma unroll
      for (int n = 0; n < 4; ++n) {
        const size_t off = kbt + ((size_t)(ks * 4 + lk) * 128 + wc * 64 + n * 16 + lr) * 8;
        bf16x8 bh_ = ldfrag(Khi + off);
        bf16x8 bl_ = ldfrag(Klo + off);
        #pragma unroll
        for (int m = 0; m < 4; ++m) {
          MFMA(a1[m][n], ah[m], bh_);
          MFMA(a1[m][n], ah[m], bl_);
          MFMA(a1[m][n], al[m], bh_);
        }
      }
    }
    #pragma unroll
    for (int m = 0; m < 4; ++m)
      #pragma unroll
      for (int n = 0; n < 4; ++n)
        #pragma unroll
        for (int q = 0; q < 4; ++q) {
          const int row = wr * 64 + m * 16 + lk * 4 + q;
          const int c   = wc * 64 + n * 16 + lr;
          const float e = __expf(a1[m][n][q] * 0.0625f);
          ushort hi, lo;
          split2(e, hi, lo);
          const int idx = (((c >> 3) * 128) + row) * 8 + (c & 7);
          pAhi[idx] = hi; pAlo[idx] = lo;
        }
  }
  __syncthreads();

  for (int cc = 0; cc < 4; ++cc) {
    if (cc) __syncthreads();
    {
      const int k = tid >> 1, c0 = (tid & 1) * 64;
      const float* vp = SolT + (size_t)k * LDV + cc * 128 + c0;
      for (int c = 0; c < 64; ++c) {
        ushort hi, lo;
        split2(vp[c], hi, lo);
        const int idx = (((k >> 3) * 128) + c0 + c) * 8 + (k & 7);
        shi[idx] = hi; slo[idx] = lo;
      }
    }
    __syncthreads();
    f32x4 u[4][4];
    #pragma unroll
    for (int i = 0; i < 4; ++i)
      #pragma unroll
      for (int j = 0; j < 4; ++j) u[i][j] = (f32x4)(0.f);
    #pragma unroll
    for (int ks = 0; ks < 4; ++ks) {
      bf16x8 ah[4], al[4];
      #pragma unroll
      for (int m = 0; m < 4; ++m) {
        const int idx = (((ks * 4 + lk) * 128) + wr * 64 + m * 16 + lr) * 8;
        ah[m] = ldfrag(&pAhi[idx]);
        al[m] = ldfrag(&pAlo[idx]);
      }
      #pragma unroll
      for (int n = 0; n < 4; ++n) {
        const int idx = (((ks * 4 + lk) * 128) + wc * 64 + n * 16 + lr) * 8;
        bf16x8 bh_ = ldfrag(&shi[idx]);
        bf16x8 bl_ = ldfrag(&slo[idx]);
        #pragma unroll
        for (int m = 0; m < 4; ++m) {
          MFMA(u[m][n], ah[m], bh_);
          MFMA(u[m][n], ah[m], bl_);
          MFMA(u[m][n], al[m], bh_);
        }
      }
    }
    float nv[4][4][4];
    #pragma unroll
    for (int m = 0; m < 4; ++m)
      #pragma unroll
      for (int n = 0; n < 4; ++n) {
        const int col = wc * 64 + n * 16 + lr;
        #pragma unroll
        for (int q = 0; q < 4; ++q) {
          const int row = wr * 64 + m * 16 + lk * 4 + q;
          const float v = Vib[(size_t)row * LDV + cc * 128 + col] - u[m][n][q];
          nv[m][n][q] = v;
          if (!lead) Vib[(size_t)row * LDV + cc * 128 + col] = v;
        }
      }
    if (lead) {
      __syncthreads();   // all reads of shi/slo done; reuse them for rhs
      #pragma unroll
      for (int m = 0; m < 4; ++m)
        #pragma unroll
        for (int n = 0; n < 4; ++n) {
          const int col = wc * 64 + n * 16 + lr;
          #pragma unroll
          for (int q = 0; q < 4; ++q) {
            const int row = wr * 64 + m * 16 + lk * 4 + q;
            ushort hi, lo;
            split2(nv[m][n][q], hi, lo);
            const int idx = (((row >> 3) * 128) + col) * 8 + (row & 7);
            shi[idx] = hi; slo[idx] = lo;
          }
        }
      __syncthreads();
      f32x4 s2[4][4];
      #pragma unroll
      for (int i = 0; i < 4; ++i)
        #pragma unroll
        for (int j = 0; j < 4; ++j) s2[i][j] = (f32x4)(0.f);
      const size_t wb = (size_t)(bh * 16 + ib) * 16384;
      #pragma unroll
      for (int ks = 0; ks < 4; ++ks) {
        bf16x8 ah[4], al[4];
        #pragma unroll
        for (int m = 0; m < 4; ++m) {
          const size_t off = wb + ((size_t)(ks * 4 + lk) * 128 + wr * 64 + m * 16 + lr) * 8;
          ah[m] = ldfrag(Whi + off);
          al[m] = ldfrag(Wlo + off);
        }
        #pragma unroll
        for (int n = 0; n < 4; ++n) {
          const int idx = (((ks * 4 + lk) * 128) + wc * 64 + n * 16 + lr) * 8;
          bf16x8 bh_ = ldfrag(&shi[idx]);
          bf16x8 bl_ = ldfrag(&slo[idx]);
          #pragma unroll
          for (int m = 0; m < 4; ++m) {
            MFMA(s2[m][n], ah[m], bh_);
            MFMA(s2[m][n], ah[m], bl_);
            MFMA(s2[m][n], al[m], bh_);
          }
        }
      }
      #pragma unroll
      for (int m = 0; m < 4; ++m)
        #pragma unroll
        for (int n = 0; n < 4; ++n) {
          const int col = wc * 64 + n * 16 + lr;
          #pragma unroll
          for (int q = 0; q < 4; ++q) {
            const int row = wr * 64 + m * 16 + lk * 4 + q;
            Vib[(size_t)row * LDV + cc * 128 + col] = s2[m][n][q];
          }
        }
    }
  }
}

// ---------------------------------------------------------------------------
// o_kernel: O = tril(exp(Q K^T/16)) @ sol, fully split-bf16 MFMA.
// Grid = 256 flat blocks; each runs tasks (ib, 15-ib) on one 128-col quarter
// of one bh (perfect balance, weight 17). Writes Opack (bf16 A-pack).
// ---------------------------------------------------------------------------
__global__ __launch_bounds__(256) void o_kernel(
    const ushort* __restrict__ Qhi, const ushort* __restrict__ Qlo,
    const ushort* __restrict__ Khi, const ushort* __restrict__ Klo,
    const float* __restrict__ V, ushort* __restrict__ Opack)
{
  __shared__ __align__(16) ushort Phi_s[16 * 128 * 8];  // 32 KB
  __shared__ __align__(16) ushort Plo_s[16 * 128 * 8];  // 32 KB
  __shared__ __align__(16) ushort shi[16 * 128 * 8];    // 32 KB
  __shared__ __align__(16) ushort slo[16 * 128 * 8];    // 32 KB
  const int bid = blockIdx.x;
  const int bh  = bid & 7;
  const int cq  = (bid >> 3) & 3;
  const int ib0 = bid >> 5;           // 0..7
  const int b = bh >> 2, h = bh & 3;
  const int tid = threadIdx.x;
  const int lane = tid & 63, w = tid >> 6;
  const int wr = w >> 1, wc = w & 1, lr = lane & 15, lk = lane >> 4;
  const float* Vhead = V + (size_t)b * SEQ * LDV + h * 512 + cq * 128;

  for (int task = 0; task < 2; ++task) {
    const int ib = task ? (15 - ib0) : ib0;
    const size_t qb = (size_t)(bh * 16 + ib) * 32768;
    f32x4 acc[4][4];
    #pragma unroll
    for (int i = 0; i < 4; ++i)
      #pragma unroll
      for (int j = 0; j < 4; ++j) acc[i][j] = (f32x4)(0.f);

    for (int jb = 0; jb <= ib; ++jb) {
      // Gram: s = Q_ib . K_jb^T (split, 3-term)
      f32x4 s1[4][4];
      #pragma unroll
      for (int i = 0; i < 4; ++i)
        #pragma unroll
        for (int j = 0; j < 4; ++j) s1[i][j] = (f32x4)(0.f);
      const size_t kb = (size_t)(bh * 16 + jb) * 32768;
      #pragma unroll
      for (int ks = 0; ks < 8; ++ks) {
        bf16x8 ah[4], al[4];
        #pragma unroll
        for (int m = 0; m < 4; ++m) {
          const size_t off = qb + ((size_t)(ks * 4 + lk) * 128 + wr * 64 + m * 16 + lr) * 8;
          ah[m] = ldfrag(Qhi + off);
          al[m] = ldfrag(Qlo + off);
        }
        #pragma unroll
        for (int n = 0; n < 4; ++n) {
          const size_t off = kb + ((size_t)(ks * 4 + lk) * 128 + wc * 64 + n * 16 + lr) * 8;
          bf16x8 bh_ = ldfrag(Khi + off);
          bf16x8 bl_ = ldfrag(Klo + off);
          #pragma unroll
          for (int m = 0; m < 4; ++m) {
            MFMA(s1[m][n], ah[m], bh_);
            MFMA(s1[m][n], ah[m], bl_);
            MFMA(s1[m][n], al[m], bh_);
          }
        }
      }
      if (jb || task) __syncthreads();   // previous LDS consumers done
      // P = exp(s/16), tril-masked on diagonal block; split into A-pack
      #pragma unroll
      for (int m = 0; m < 4; ++m)
        #pragma unroll
        for (int n = 0; n < 4; ++n)
          #pragma unroll
          for (int q = 0; q < 4; ++q) {
            const int row = wr * 64 + m * 16 + lk * 4 + q;
            const int c   = wc * 64 + n * 16 + lr;
            float e = __expf(s1[m][n][q] * 0.0625f);
            if (jb == ib && c > row) e = 0.f;
            ushort hi, lo;
            split2(e, hi, lo);
            const int idx = (((c >> 3) * 128) + row) * 8 + (c & 7);
            Phi_s[idx] = hi; Plo_s[idx] = lo;
          }
      // stage sol chunk (rows jb*128.., this quarter's 128 cols), split
      {
        const int k = tid >> 1, c0 = (tid & 1) * 64;
        const float* vp = Vhead + (size_t)(jb * 128 + k) * LDV + c0;
        for (int c = 0; c < 64; ++c) {
          ushort hi, lo;
          split2(vp[c], hi, lo);
          const int idx = (((k >> 3) * 128) + c0 + c) * 8 + (k & 7);
          shi[idx] = hi; slo[idx] = lo;
        }
      }
      __syncthreads();
      // acc += P @ sol (split, 3-term)
      #pragma unroll
      for (int ks = 0; ks < 4; ++ks) {
        bf16x8 ah[4], al[4];
        #pragma unroll
        for (int m = 0; m < 4; ++m) {
          const int idx = (((ks * 4 + lk) * 128) + wr * 64 + m * 16 + lr) * 8;
          ah[m] = ldfrag(&Phi_s[idx]);
          al[m] = ldfrag(&Plo_s[idx]);
        }
        #pragma unroll
        for (int n = 0; n < 4; ++n) {
          const int idx = (((ks * 4 + lk) * 128) + wc * 64 + n * 16 + lr) * 8;
          bf16x8 bh_ = ldfrag(&shi[idx]);
          bf16x8 bl_ = ldfrag(&slo[idx]);
          #pragma unroll
          for (int m = 0; m < 4; ++m) {
            MFMA(acc[m][n], ah[m], bh_);
            MFMA(acc[m][n], ah[m], bl_);
            MFMA(acc[m][n], al[m], bh_);
          }
        }
      }
    }
    // write Opack (bf16 A-pack over the 2048 O-cols, K8 = 256)
    const int row_blk = b * 16 + ib;
    #pragma unroll
    for (int m = 0; m < 4; ++m)
      #pragma unroll
      for (int n = 0; n < 4; ++n) {
        const int col = h * 512 + cq * 128 + wc * 64 + n * 16 + lr;
        #pragma unroll
        for (int q = 0; q < 4; ++q) {
          const int row = wr * 64 + m * 16 + lk * 4 + q;
          Opack[((size_t)row_blk * 256 + (col >> 3)) * 1024 + row * 8 + (col & 7)] =
              f2bf(acc[m][n][q]);
        }
      }
  }
}

// ---------------------------------------------------------------------------
extern "C" void kernel_launch(void* const* d_in, const int* in_sizes, int n_in,
                              void* d_out, int out_size, void* d_ws, size_t ws_size,
                              hipStream_t stream)
{
  const float* x  = (const float*)d_in[0];
  const float* Wq = (const float*)d_in[1];
  const float* Wk = (const float*)d_in[2];
  const float* Wv = (const float*)d_in[3];
  const float* Wo = (const float*)d_in[4];
  float* out = (float*)d_out;

  // Workspace (84 MB), phase-aliased:
  //  [0,16):  xpack(8) + Wqp/Wkp/Wvp(8)  ->  Qhi(8) + Qlo(8)
  //  [16,20): Wop (alive till end)
  //  [20,36): Q fp32  ->  Khi(8) + Klo(8)
  //  [36,52): K fp32  ->  Whi(4)@36 + Wlo(4)@40  ->  Opack(16)@36
  //  [52,84): V fp32 (-> sol, alive through o_kernel)
  char* base = (char*)d_ws;
  ushort* xpack = (ushort*)(base);
  ushort* Wqp   = (ushort*)(base + (8u  << 20));
  ushort* Wkp   = (ushort*)(base + (10u << 20));
  ushort* Wvp   = (ushort*)(base + (12u << 20));
  ushort* Wop   = (ushort*)(base + (16u << 20));
  float*  Q     = (float*) (base + (20u << 20));
  float*  K     = (float*) (base + (36u << 20));
  float*  V     = (float*) (base + (52u << 20));
  ushort* Qhi   = (ushort*)(base);
  ushort* Qlo   = (ushort*)(base + (8u  << 20));
  ushort* Khi   = (ushort*)(base + (20u << 20));
  ushort* Klo   = (ushort*)(base + (28u << 20));
  ushort* Whi   = (ushort*)(base + (36u << 20));
  ushort* Wlo   = (ushort*)(base + (40u << 20));
  ushort* Opack = (ushort*)(base + (36u << 20));

  // Pack inputs
  pack_x_kernel<<<(NROW * 128) / 256, 256, 0, stream>>>(x, xpack);
  pack_w_kernel<<<(1024 * 1024 / 8) / 256, 256, 0, stream>>>(Wq, Wqp, 1024, 1024);
  pack_w_kernel<<<(1024 * 1024 / 8) / 256, 256, 0, stream>>>(Wk, Wkp, 1024, 1024);
  pack_w_kernel<<<(1024 * 2048 / 8) / 256, 256, 0, stream>>>(Wv, Wvp, 1024, 2048);
  pack_w_kernel<<<(2048 * 1024 / 8) / 256, 256, 0, stream>>>(Wo, Wop, 2048, 1024);

  // Projections (bf16 MFMA, fp32 out)
  gemm_bf16<<<dim3(DM / 128, NROW / 128), 256, 0, stream>>>(xpack, Wqp, Q, NROW, DM, DM);
  gemm_bf16<<<dim3(DM / 128, NROW / 128), 256, 0, stream>>>(xpack, Wkp, K, NROW, DM, DM);
  gemm_bf16<<<dim3(LDV / 128, NROW / 128), 256, 0, stream>>>(xpack, Wvp, V, NROW, LDV, DM);

  // RoPE, then split-pack Q (into dead pack region) and K (into dead Q region)
  rope_kernel<<<(NROW * 4 * 128) / 256, 256, 0, stream>>>(Q, K);
  pack_split_kernel<<<(NROW * 128) / 256, 256, 0, stream>>>(Q, Qhi, Qlo);
  pack_split_kernel<<<(NROW * 128) / 256, 256, 0, stream>>>(K, Khi, Klo);

  // Diagonal-block inverses, then the 16-step split-MFMA solve (in place on V)
  winv_kernel<<<dim3(NBLK, 8), 256, 0, stream>>>(Khi, Klo, Whi, Wlo);
  apply_w0_kernel<<<8, 256, 0, stream>>>(Whi, Wlo, V);
  for (int t = 0; t < NBLK - 1; ++t)
    solve_step_kernel<<<dim3(NBLK - 1 - t, 8), 256, 0, stream>>>(Khi, Klo, Whi, Wlo, V, t);

  // O = tril(exp(QK^T/16)) @ sol  -> bf16 Opack (overwrites Whi/Wlo)
  o_kernel<<<256, 256, 0, stream>>>(Qhi, Qlo, Khi, Klo, V, Opack);

  // out = O @ Wo (bf16 MFMA)
  gemm_bf16<<<dim3(DM / 128, NROW / 128), 256, 0, stream>>>(Opack, Wop, out, NROW, DM, LDV);
}